// Round 2
// baseline (449.704 us; speedup 1.0000x reference)
//
#include <hip/hip_runtime.h>

#define N_NODES 40000
#define N_EDGES 640000
#define IN_F 128
#define HID_F 256
#define CLS_F 40
#define MB 32   // nodes per block in fused MLP (N_NODES % MB == 0)

// ---------------- small float4 helpers ----------------

__device__ __forceinline__ float4 f4add(float4 a, float4 b) {
    return make_float4(a.x + b.x, a.y + b.y, a.z + b.z, a.w + b.w);
}
__device__ __forceinline__ float4 f4fma(float s, float4 w, float4 a) {
    return make_float4(fmaf(s, w.x, a.x), fmaf(s, w.y, a.y),
                       fmaf(s, w.z, a.z), fmaf(s, w.w, a.w));
}
__device__ __forceinline__ float4 f4scale(float4 v, float s) {
    return make_float4(v.x * s, v.y * s, v.z * s, v.w * s);
}

// ---------------- CSR build ----------------

__global__ void k_count(const int* __restrict__ dst, int* __restrict__ counts) {
    int e = blockIdx.x * blockDim.x + threadIdx.x;
    if (e < N_EDGES) atomicAdd(&counts[dst[e]], 1);
}

__global__ void k_scan1(const int* __restrict__ counts, int* __restrict__ bsum) {
    __shared__ int s[256];
    int i = blockIdx.x * 256 + threadIdx.x;
    s[threadIdx.x] = (i < N_NODES) ? counts[i] : 0;
    __syncthreads();
    for (int off = 128; off > 0; off >>= 1) {
        if (threadIdx.x < off) s[threadIdx.x] += s[threadIdx.x + off];
        __syncthreads();
    }
    if (threadIdx.x == 0) bsum[blockIdx.x] = s[0];
}

__global__ void k_scan2(int* __restrict__ bsum, int nb) {
    if (blockIdx.x == 0 && threadIdx.x == 0) {
        int run = 0;
        for (int b = 0; b < nb; b++) { int t = bsum[b]; bsum[b] = run; run += t; }
    }
}

// scan3 + norm fused: writes rowptr/cursor and norm/norm2
__global__ void k_scan3(const int* __restrict__ counts, const int* __restrict__ bsum,
                        int* __restrict__ rowptr, int* __restrict__ cursor,
                        float* __restrict__ norm, float* __restrict__ norm2) {
    __shared__ int s[256];
    int t = threadIdx.x;
    int i = blockIdx.x * 256 + t;
    int v = (i < N_NODES) ? counts[i] : 0;
    s[t] = v;
    __syncthreads();
    for (int off = 1; off < 256; off <<= 1) {
        int x = (t >= off) ? s[t - off] : 0;
        __syncthreads();
        s[t] += x;
        __syncthreads();
    }
    if (i < N_NODES) {
        int excl = s[t] - v + bsum[blockIdx.x];
        rowptr[i] = excl;
        cursor[i] = excl;
        float r = rsqrtf(fmaxf((float)v, 1.0f));
        norm[i] = r;
        norm2[i] = r * r;
    }
}

__global__ void k_fill(const int* __restrict__ src, const int* __restrict__ dst,
                       int* __restrict__ cursor, int* __restrict__ csr_src) {
    int e = blockIdx.x * blockDim.x + threadIdx.x;
    if (e < N_EDGES) {
        int d = dst[e];
        int p = atomicAdd(&cursor[d], 1);
        csr_src[p] = src[e];
    }
}

// ---------------- pre-scale: g0 = features * norm[node] ----------------

__global__ void k_pre(const float* __restrict__ f, const float* __restrict__ norm,
                      float* __restrict__ g0) {
    int i4 = blockIdx.x * 256 + threadIdx.x;
    if (i4 < N_NODES * (IN_F / 4)) {
        int node = i4 >> 5;                 // IN_F/4 = 32 float4 per row
        float4 v = ((const float4*)f)[i4];
        ((float4*)g0)[i4] = f4scale(v, norm[node]);
    }
}

// ---------------- W2 transpose: W2t[c][j] = W2[j][c] ----------------

__global__ void k_w2t(const float* __restrict__ W2, float* __restrict__ W2t) {
    int idx = blockIdx.x * 256 + threadIdx.x;
    if (idx < CLS_F * HID_F) {
        int c = idx >> 8, j = idx & 255;    // HID_F = 256
        W2t[idx] = W2[j * CLS_F + c];
    }
}

// ---------------- propagation hop (gather, no atomics) ----------------
// out[n][:] = oscale(n) * sum_{s in in-edges(n)} in[s][:]
// 32 lanes per node, float4 per lane. 4-way unroll -> 4 row gathers in flight.

__global__ __launch_bounds__(256) void k_hop(
        const float* __restrict__ gin, float* __restrict__ gout,
        const int* __restrict__ csr_src, const int* __restrict__ rowptr,
        const int* __restrict__ counts, const float* __restrict__ oscale,
        int use_oscale) {
    int gid  = blockIdx.x * 8 + (threadIdx.x >> 5);
    int lane = threadIdx.x & 31;
    if (gid >= N_NODES) return;
    int start = rowptr[gid];
    int cnt   = counts[gid];
    const int* cp = csr_src + start;
    float4 a0 = make_float4(0.f, 0.f, 0.f, 0.f);
    float4 a1 = a0, a2 = a0, a3 = a0;
    int i = 0;
    for (; i + 4 <= cnt; i += 4) {
        int s0 = cp[i], s1 = cp[i + 1], s2 = cp[i + 2], s3 = cp[i + 3];
        float4 v0 = ((const float4*)(gin + (size_t)s0 * IN_F))[lane];
        float4 v1 = ((const float4*)(gin + (size_t)s1 * IN_F))[lane];
        float4 v2 = ((const float4*)(gin + (size_t)s2 * IN_F))[lane];
        float4 v3 = ((const float4*)(gin + (size_t)s3 * IN_F))[lane];
        a0 = f4add(a0, v0);
        a1 = f4add(a1, v1);
        a2 = f4add(a2, v2);
        a3 = f4add(a3, v3);
    }
    for (; i < cnt; i++) {
        int s = cp[i];
        float4 v = ((const float4*)(gin + (size_t)s * IN_F))[lane];
        a0 = f4add(a0, v);
    }
    float4 r = f4add(f4add(a0, a1), f4add(a2, a3));
    if (use_oscale) r = f4scale(r, oscale[gid]);
    ((float4*)(gout + (size_t)gid * IN_F))[lane] = r;
}

// ---------------- fused MLP: (h2*norm) @ W1 + b1 -> relu -> @ W2 + b2 ----------------
// MB=32 nodes/block, 256 threads. GEMM1 register tile: 8 nodes x 4 hid cols.
// hg = tid & 63 (64 groups x 4 cols = 256), ng = tid >> 6 (4 groups x 8 nodes = 32).
// A-reads from LDS are full-wave broadcasts (free); W1 read coalesced from L2.

__global__ __launch_bounds__(256) void k_mlp(
        const float* __restrict__ h2, const float* __restrict__ norm,
        const float* __restrict__ W1, const float* __restrict__ b1,
        const float* __restrict__ W2t, const float* __restrict__ b2,
        float* __restrict__ out) {
    __shared__ __align__(16) float hs[MB * IN_F];    // 16 KB
    __shared__ __align__(16) float ts[MB * HID_F];   // 32 KB
    int n0 = blockIdx.x * MB;
    int t  = threadIdx.x;
    int hg = t & 63;
    int ng = t >> 6;

    // stage 32 node rows (x trailing norm), float4 coalesced
    float4* hs4 = (float4*)hs;
    const float4* h24 = (const float4*)(h2 + (size_t)n0 * IN_F);
    #pragma unroll
    for (int p = 0; p < (MB * IN_F / 4) / 256; p++) {
        int i4 = t + p * 256;
        int m = i4 >> 5;
        hs4[i4] = f4scale(h24[i4], norm[n0 + m]);
    }
    __syncthreads();

    // GEMM1
    float4 acc[8];
    #pragma unroll
    for (int i = 0; i < 8; i++) acc[i] = make_float4(0.f, 0.f, 0.f, 0.f);
    const float4* w1p = (const float4*)W1 + hg;          // row stride 64 float4
    const float4* ap  = hs4 + (size_t)(ng * 8) * (IN_F / 4);
    for (int k4 = 0; k4 < IN_F / 4; k4++) {
        float4 w0 = w1p[(k4 * 4 + 0) * 64];
        float4 w1v = w1p[(k4 * 4 + 1) * 64];
        float4 w2v = w1p[(k4 * 4 + 2) * 64];
        float4 w3v = w1p[(k4 * 4 + 3) * 64];
        #pragma unroll
        for (int i = 0; i < 8; i++) {
            float4 h4 = ap[i * (IN_F / 4) + k4];         // full-wave broadcast
            acc[i] = f4fma(h4.x, w0, acc[i]);
            acc[i] = f4fma(h4.y, w1v, acc[i]);
            acc[i] = f4fma(h4.z, w2v, acc[i]);
            acc[i] = f4fma(h4.w, w3v, acc[i]);
        }
    }
    float4 bb = ((const float4*)b1)[hg];
    float4* ts4 = (float4*)ts;
    #pragma unroll
    for (int i = 0; i < 8; i++) {
        float4 v;
        v.x = fmaxf(acc[i].x + bb.x, 0.f);
        v.y = fmaxf(acc[i].y + bb.y, 0.f);
        v.z = fmaxf(acc[i].z + bb.z, 0.f);
        v.w = fmaxf(acc[i].w + bb.w, 0.f);
        ts4[(size_t)(ng * 8 + i) * (HID_F / 4) + hg] = v;
    }
    __syncthreads();

    // GEMM2: 32x40 outputs, thread per output, j4-vectorized
    for (int o = t; o < MB * CLS_F; o += 256) {
        int m = o / CLS_F, c = o % CLS_F;
        const float4* tr = (const float4*)(ts + (size_t)m * HID_F);
        const float4* wr = (const float4*)(W2t + (size_t)c * HID_F);
        float s = b2[c];
        for (int j4 = 0; j4 < HID_F / 4; j4++) {
            float4 a = tr[j4];      // 2-way broadcast within wave (free)
            float4 w = wr[j4];      // L1/L2-hot
            s = fmaf(a.x, w.x, s);
            s = fmaf(a.y, w.y, s);
            s = fmaf(a.z, w.z, s);
            s = fmaf(a.w, w.w, s);
        }
        out[(size_t)(n0 + m) * CLS_F + c] = s;
    }
}

// ---------------- launch ----------------

extern "C" void kernel_launch(void* const* d_in, const int* in_sizes, int n_in,
                              void* d_out, int out_size, void* d_ws, size_t ws_size,
                              hipStream_t stream) {
    const float* features = (const float*)d_in[0];
    const int*   src      = (const int*)d_in[1];
    const int*   dst      = (const int*)d_in[2];
    const float* W1       = (const float*)d_in[3];
    const float* b1       = (const float*)d_in[4];
    const float* W2       = (const float*)d_in[5];
    const float* b2       = (const float*)d_in[6];
    float*       out      = (float*)d_out;

    char* ws = (char*)d_ws;
    size_t off = 0;
    auto alloc = [&](size_t bytes) -> void* {
        void* p = ws + off;
        off += (bytes + 255) & ~(size_t)255;
        return p;
    };
    int*   counts = (int*)alloc((size_t)N_NODES * 4);
    int*   rowptr = (int*)alloc((size_t)N_NODES * 4);
    int*   cursor = (int*)alloc((size_t)N_NODES * 4);
    int*   bsum   = (int*)alloc(256 * 4);
    float* norm   = (float*)alloc((size_t)N_NODES * 4);
    float* norm2  = (float*)alloc((size_t)N_NODES * 4);
    float* W2t    = (float*)alloc((size_t)CLS_F * HID_F * 4);
    int*   csr    = (int*)alloc((size_t)N_EDGES * 4);
    float* bufA   = (float*)alloc((size_t)N_NODES * IN_F * 4);
    float* bufB   = (float*)alloc((size_t)N_NODES * IN_F * 4);

    hipMemsetAsync(counts, 0, (size_t)N_NODES * 4, stream);

    int nb = (N_NODES + 255) / 256;   // 157
    k_count<<<(N_EDGES + 255) / 256, 256, 0, stream>>>(dst, counts);
    k_scan1<<<nb, 256, 0, stream>>>(counts, bsum);
    k_scan2<<<1, 64, 0, stream>>>(bsum, nb);
    k_scan3<<<nb, 256, 0, stream>>>(counts, bsum, rowptr, cursor, norm, norm2);
    k_fill<<<(N_EDGES + 255) / 256, 256, 0, stream>>>(src, dst, cursor, csr);
    k_w2t<<<(CLS_F * HID_F + 255) / 256, 256, 0, stream>>>(W2, W2t);

    // g0 = features * norm  -> bufA
    k_pre<<<(N_NODES * (IN_F / 4) + 255) / 256, 256, 0, stream>>>(features, norm, bufA);
    // hop1: bufB = norm2[dst] * sum(g0[src])   (g1, pre-scaled for hop2)
    k_hop<<<(N_NODES + 7) / 8, 256, 0, stream>>>(bufA, bufB, csr, rowptr, counts, norm2, 1);
    // hop2: bufA = sum(g1[src])                (trailing norm folded into MLP)
    k_hop<<<(N_NODES + 7) / 8, 256, 0, stream>>>(bufB, bufA, csr, rowptr, counts, norm2, 0);

    k_mlp<<<N_NODES / MB, 256, 0, stream>>>(bufA, norm, W1, b1, W2t, b2, out);
}